// Round 8
// baseline (44.769 us; speedup 1.0000x reference)
//
#include <hip/hip_runtime.h>
#include <hip/hip_cooperative_groups.h>

namespace cg = cooperative_groups;

// BoundaryLoss, SINGLE cooperative-kernel version.
// loss = sum sigmoid(logits[b,c,q]) * sqrt(edt2[b,q]) / (N4*C)
// edt2 = separable squared-EDT of bg (reference pass order B,D,H,W).
//
// Bit-exactness ladder (valid for ANY input, perf tuned for benign input):
//  (1) ring-scan early exit: EDT values >= 0, so ring-r candidates >= r^2;
//      skipping them when r^2 >= best leaves the fp32 min unchanged.
//  (2) nested lazy evaluation: W consumes fH on-the-fly, fH consumes fD,
//      fD consumes fB; by induction identical to the materialized passes.
//  (3) fB(b,q)==0 whenever targets[b,q] is valid (min(0,x+1)=0, x>=0), and
//      fB==0 => all downstream passes return 0. Valid target => dist==0
//      with zero extra loads.
//  (4) dist==0 => contribution is +0; skipping the logits load/add leaves
//      the fp32 accumulator bit-identical.
//
// R7 lesson: every graph node costs ~4.5us; work is ~3us. So: ONE node.
// Cross-block combine via cooperative grid sync (harness-supported),
// partials as plain stores in d_ws (fully rewritten every call -> no
// cross-call state, poison-immune), block 0 does a fixed-order final
// reduction -> deterministic for any input. No atomics anywhere.

#define EDT_INF 1e10f

constexpr int Bb = 2, Cc = 4, Dd = 64, Hh = 96, Ww = 96;
constexpr int HW  = Hh * Ww;          // 9216
constexpr int DHW = Dd * HW;          // 589824
constexpr int N4  = Bb * DHW;         // 1179648
constexpr int NI4 = N4 / 4;           // 294912 int4 chunks
constexpr int NBLK = 288;             // 288*256*4 == NI4 exactly
constexpr int I4_PER_THREAD = 4;

// ---- lazy evaluators (exact; only touched on the slow path) ----
__device__ __forceinline__ float evalB(const int* __restrict__ t, int b, int q) {
    int tv = t[b * DHW + q];
    float fb = (tv >= 0 && tv < Cc) ? 0.0f : EDT_INF;
    if (fb == 0.0f) return 0.0f;              // min(0, x+1) = 0 exactly
    int to = t[(1 - b) * DHW + q];
    float fo = (to >= 0 && to < Cc) ? 0.0f : EDT_INF;
    return fminf(fb, fo + 1.0f);
}

__device__ float evalD(const int* __restrict__ t, int b, int d, int hw) {
    float best = evalB(t, b, d * HW + hw);
    for (int r = 1; r < Dd; ++r) {
        float r2 = (float)(r * r);
        if (r2 >= best) break;
        int jm = d - r, jp = d + r;
        if (jm >= 0) best = fminf(best, evalB(t, b, jm * HW + hw) + r2);
        if (jp < Dd) best = fminf(best, evalB(t, b, jp * HW + hw) + r2);
    }
    return best;
}

__device__ float evalH(const int* __restrict__ t, int b, int d, int h, int w) {
    float best = evalD(t, b, d, h * Ww + w);
    for (int r = 1; r < Hh; ++r) {
        float r2 = (float)(r * r);
        if (r2 >= best) break;
        int jm = h - r, jp = h + r;
        if (jm >= 0) best = fminf(best, evalD(t, b, d, jm * Ww + w) + r2);
        if (jp < Hh) best = fminf(best, evalD(t, b, d, jp * Ww + w) + r2);
    }
    return best;
}

__device__ float evalW(const int* __restrict__ t, int b, int d, int h, int w) {
    float best = evalH(t, b, d, h, w);
    for (int r = 1; r < Ww; ++r) {
        float r2 = (float)(r * r);
        if (r2 >= best) break;
        int jm = w - r, jp = w + r;
        if (jm >= 0) best = fminf(best, evalH(t, b, d, h, jm) + r2);
        if (jp < Ww) best = fminf(best, evalH(t, b, d, h, jp) + r2);
    }
    return best;
}

// ---- the single cooperative kernel ----
__global__ __launch_bounds__(256) void kf_coop(const int* __restrict__ targets,
                                               const float* __restrict__ logits,
                                               float* __restrict__ partials,
                                               float* __restrict__ out) {
    float acc = 0.0f;
    // Each block owns 1024 consecutive int4 chunks; per iteration the wave
    // reads 256 consecutive int4 (4 KB contiguous) -> fully coalesced.
    const int base = blockIdx.x * (256 * I4_PER_THREAD);
    #pragma unroll
    for (int k = 0; k < I4_PER_THREAD; ++k) {
        const int i4 = base + k * 256 + threadIdx.x;
        const int e = i4 * 4;
        const int4 t4 = *reinterpret_cast<const int4*>(&targets[e]);
        const bool fast = (t4.x >= 0 && t4.x < Cc) && (t4.y >= 0 && t4.y < Cc) &&
                          (t4.z >= 0 && t4.z < Cc) && (t4.w >= 0 && t4.w < Cc);
        if (!fast) {
            // general lazy EDT + weighted sum for these 4 voxels
            int b   = e / DHW;
            int rem = e - b * DHW;          // d*HW + h*Ww + w0
            int d   = rem / HW;
            int r2_ = rem - d * HW;
            int h   = r2_ / Ww;
            int w0  = r2_ - h * Ww;
            for (int l = 0; l < 4; ++l) {
                float dist = sqrtf(evalW(targets, b, d, h, w0 + l));
                if (dist != 0.0f) {
                    const float* lp = logits + (size_t)b * Cc * DHW + rem + l;
                    #pragma unroll
                    for (int c = 0; c < Cc; ++c) {
                        float x = lp[(size_t)c * DHW];
                        acc += dist * __builtin_amdgcn_rcpf(1.0f + __expf(-x));
                    }
                }
            }
        }
    }

    // block reduce (fixed order)
    #pragma unroll
    for (int off = 32; off > 0; off >>= 1) acc += __shfl_down(acc, off, 64);
    __shared__ float sw[4];
    const int lane = threadIdx.x & 63, wid = threadIdx.x >> 6;
    if (lane == 0) sw[wid] = acc;
    __syncthreads();
    if (threadIdx.x == 0)
        partials[blockIdx.x] = ((sw[0] + sw[1]) + sw[2]) + sw[3];

    // grid-wide barrier (memory-visibility included), then block 0 combines
    cg::this_grid().sync();

    if (blockIdx.x == 0) {
        float a2 = partials[threadIdx.x];                       // 0..255
        if ((int)threadIdx.x < NBLK - 256) a2 += partials[256 + threadIdx.x];
        #pragma unroll
        for (int off = 32; off > 0; off >>= 1) a2 += __shfl_down(a2, off, 64);
        __shared__ float sw2[4];
        if (lane == 0) sw2[wid] = a2;
        __syncthreads();
        if (threadIdx.x == 0)
            out[0] = (((sw2[0] + sw2[1]) + sw2[2]) + sw2[3]) *
                     (1.0f / ((float)N4 * (float)Cc));
    }
}

extern "C" void kernel_launch(void* const* d_in, const int* in_sizes, int n_in,
                              void* d_out, int out_size, void* d_ws, size_t ws_size,
                              hipStream_t stream) {
    const int*   targets = (const int*)d_in[1];     // [B,D,H,W] int32
    const float* logits  = (const float*)d_in[0];   // [B,C,D,H,W] fp32
    float* out = (float*)d_out;
    float* partials = (float*)d_ws;                 // NBLK floats

    void* args[] = {(void*)&targets, (void*)&logits, (void*)&partials, (void*)&out};
    hipLaunchCooperativeKernel((const void*)kf_coop, dim3(NBLK), dim3(256),
                               args, 0, stream);
}

// Round 9
// 11.596 us; speedup vs baseline: 3.8606x; 3.8606x over previous
//
#include <hip/hip_runtime.h>

// BoundaryLoss, 2-kernel lazy-evaluation version (champion config, R6).
// loss = sum sigmoid(logits[b,c,q]) * sqrt(edt2[b,q]) / (N4*C)
// edt2 = separable squared-EDT of bg (reference pass order B,D,H,W).
//
// Bit-exactness ladder (valid for ANY input, perf tuned for benign input):
//  (1) ring-scan early exit: EDT values >= 0, so ring-r candidates >= r^2;
//      skipping them when r^2 >= best leaves the fp32 min unchanged.
//  (2) nested lazy evaluation: W consumes fH on-the-fly, fH consumes fD,
//      fD consumes fB; by induction identical to the materialized passes.
//  (3) fB(b,q)==0 whenever targets[b,q] is valid (min(0,x+1)=0, x>=0), and
//      fB==0 => all downstream passes return 0. Valid target => dist==0
//      with zero extra loads.
//  (4) dist==0 => contribution is +0; skipping the logits load/add leaves
//      the fp32 accumulator bit-identical.
//
// Structural-floor ledger (MI355X, graph-replayed):
//   ~4.5 us per graph node + ~5.5 us fixed replay overhead (fit over
//   R2/R5/R6/R7: 5 nodes=28us, 4=22, 2=14.4, 2=15.3).
//   Single-node designs need a cross-block rendezvous; measured costs:
//   cooperative grid sync = +35us (R8), agent-scope ACQ_REL election =
//   +35us @1152 blocks (R4). Every rendezvous > the node it saves.
//   => 2 plain-store nodes is the floor; real work (4.7MB scan) ~2.5us.

#define EDT_INF 1e10f

constexpr int Bb = 2, Cc = 4, Dd = 64, Hh = 96, Ww = 96;
constexpr int HW  = Hh * Ww;          // 9216
constexpr int DHW = Dd * HW;          // 589824
constexpr int N4  = Bb * DHW;         // 1179648
constexpr int KF_BLOCKS = N4 / 4 / 256;   // 1152

// ---- lazy evaluators (exact; only touched on the slow path) ----
__device__ __forceinline__ float evalB(const int* __restrict__ t, int b, int q) {
    int tv = t[b * DHW + q];
    float fb = (tv >= 0 && tv < Cc) ? 0.0f : EDT_INF;
    if (fb == 0.0f) return 0.0f;              // min(0, x+1) = 0 exactly
    int to = t[(1 - b) * DHW + q];
    float fo = (to >= 0 && to < Cc) ? 0.0f : EDT_INF;
    return fminf(fb, fo + 1.0f);
}

__device__ float evalD(const int* __restrict__ t, int b, int d, int hw) {
    float best = evalB(t, b, d * HW + hw);
    for (int r = 1; r < Dd; ++r) {
        float r2 = (float)(r * r);
        if (r2 >= best) break;
        int jm = d - r, jp = d + r;
        if (jm >= 0) best = fminf(best, evalB(t, b, jm * HW + hw) + r2);
        if (jp < Dd) best = fminf(best, evalB(t, b, jp * HW + hw) + r2);
    }
    return best;
}

__device__ float evalH(const int* __restrict__ t, int b, int d, int h, int w) {
    float best = evalD(t, b, d, h * Ww + w);
    for (int r = 1; r < Hh; ++r) {
        float r2 = (float)(r * r);
        if (r2 >= best) break;
        int jm = h - r, jp = h + r;
        if (jm >= 0) best = fminf(best, evalD(t, b, d, jm * Ww + w) + r2);
        if (jp < Hh) best = fminf(best, evalD(t, b, d, jp * Ww + w) + r2);
    }
    return best;
}

__device__ float evalW(const int* __restrict__ t, int b, int d, int h, int w) {
    float best = evalH(t, b, d, h, w);
    for (int r = 1; r < Ww; ++r) {
        float r2 = (float)(r * r);
        if (r2 >= best) break;
        int jm = w - r, jp = w + r;
        if (jm >= 0) best = fminf(best, evalH(t, b, d, h, jm) + r2);
        if (jp < Ww) best = fminf(best, evalH(t, b, d, h, jp) + r2);
    }
    return best;
}

// ---- K_fused: targets -> per-block partial of sum(dist * sigmoid(logit)) ----
__global__ __launch_bounds__(256) void kf_fused(const int* __restrict__ targets,
                                                const float* __restrict__ logits,
                                                float* __restrict__ partials) {
    const int e = (blockIdx.x * 256 + threadIdx.x) * 4;   // 4 consecutive w
    const int4 t4 = *reinterpret_cast<const int4*>(&targets[e]);

    float acc = 0.0f;
    const bool fast = (t4.x >= 0 && t4.x < Cc) && (t4.y >= 0 && t4.y < Cc) &&
                      (t4.z >= 0 && t4.z < Cc) && (t4.w >= 0 && t4.w < Cc);
    if (!fast) {
        // slow path: general lazy EDT + weighted sum for these 4 voxels
        int b   = e / DHW;
        int rem = e - b * DHW;          // d*HW + h*Ww + w0
        int d   = rem / HW;
        int r2_ = rem - d * HW;
        int h   = r2_ / Ww;
        int w0  = r2_ - h * Ww;
        for (int l = 0; l < 4; ++l) {
            float dist = sqrtf(evalW(targets, b, d, h, w0 + l));
            if (dist != 0.0f) {
                const float* lp = logits + (size_t)b * Cc * DHW + rem + l;
                #pragma unroll
                for (int c = 0; c < Cc; ++c) {
                    float x = lp[(size_t)c * DHW];
                    acc += dist * __builtin_amdgcn_rcpf(1.0f + __expf(-x));
                }
            }
        }
    }

    // wave shuffle reduce (fixed order) + tiny LDS combine
    #pragma unroll
    for (int off = 32; off > 0; off >>= 1) acc += __shfl_down(acc, off, 64);
    __shared__ float sw[4];
    const int lane = threadIdx.x & 63, wid = threadIdx.x >> 6;
    if (lane == 0) sw[wid] = acc;
    __syncthreads();
    if (threadIdx.x == 0)
        partials[blockIdx.x] = ((sw[0] + sw[1]) + sw[2]) + sw[3];
}

// ---- K_final: deterministic reduction of partials + scale ----
__global__ __launch_bounds__(256) void kf_final(const float* __restrict__ partials,
                                                float* __restrict__ out) {
    float acc = 0.0f;
    for (int i = threadIdx.x; i < KF_BLOCKS; i += 256) acc += partials[i];
    #pragma unroll
    for (int off = 32; off > 0; off >>= 1) acc += __shfl_down(acc, off, 64);
    __shared__ float sw[4];
    const int lane = threadIdx.x & 63, wid = threadIdx.x >> 6;
    if (lane == 0) sw[wid] = acc;
    __syncthreads();
    if (threadIdx.x == 0)
        out[0] = (((sw[0] + sw[1]) + sw[2]) + sw[3]) *
                 (1.0f / ((float)N4 * (float)Cc));
}

extern "C" void kernel_launch(void* const* d_in, const int* in_sizes, int n_in,
                              void* d_out, int out_size, void* d_ws, size_t ws_size,
                              hipStream_t stream) {
    const float* logits  = (const float*)d_in[0];   // [B,C,D,H,W] fp32
    const int*   targets = (const int*)d_in[1];     // [B,D,H,W] int32
    float* out = (float*)d_out;

    float* partials = (float*)d_ws;                 // KF_BLOCKS floats

    kf_fused<<<dim3(KF_BLOCKS), dim3(256), 0, stream>>>(targets, logits, partials);
    kf_final<<<dim3(1), dim3(256), 0, stream>>>(partials, out);
}